// Round 13
// baseline (479.594 us; speedup 1.0000x reference)
//
#include <hip/hip_runtime.h>
#include <cstddef>

namespace {

constexpr int    Bn   = 8;
constexpr int    Cc   = 64;    // value channels
constexpr int    Cq   = 8;     // q/k channels
constexpr int    Ln   = 256;   // H == W
constexpr size_t HWn  = 65536; // H*W
constexpr size_t NPIX = (size_t)Bn * HWn; // 524288
constexpr size_t VPLANE = NPIX * 16;      // shorts per v chunk-plane

constexpr float LOG2E = 1.44269504088896f;

// workspace layout (byte offsets)
constexpr size_t WT_B = 0;                        // 80*64 fp32 weights (20 KB)
constexpr size_t QH_B = 32768;                    // NPIX*8 bf16 (8 MB)
constexpr size_t QL_B = QH_B + NPIX * 8 * 2;
constexpr size_t KH_B = QL_B + NPIX * 8 * 2;
constexpr size_t KL_B = KH_B + NPIX * 8 * 2;
constexpr size_t VB_B = KL_B + NPIX * 8 * 2;      // 4 planes x NPIX*16 bf16 (64 MB)
constexpr size_t HO_B = VB_B + NPIX * 64 * 2;     // NPIX*64 fp16 h_out (64 MB)
constexpr size_t WO_B = HO_B + NPIX * 64 * 2;     // NPIX*64 fp16 w_out (64 MB)
// total ~224 MB

typedef short bf16x8 __attribute__((ext_vector_type(8)));  // 8 bf16 (4 VGPRs)
typedef float f32x16 __attribute__((ext_vector_type(16))); // MFMA 32x32 C/D
typedef unsigned short u16x4 __attribute__((ext_vector_type(4)));

__device__ __forceinline__ float bf2f(unsigned short h) {
  union { unsigned u; float f; } c; c.u = ((unsigned)h) << 16;
  return c.f;
}
__device__ __forceinline__ float fbits(unsigned u) {
  union { unsigned u; float f; } c; c.u = u; return c.f;
}
// packed f32->bf16 RNE via HW (same rounding as the old hand-rolled f2bf):
// dst low16 = cvt(a), high16 = cvt(b)
__device__ __forceinline__ unsigned cvt_pk_bf16(float a, float b) {
  unsigned r;
  asm("v_cvt_pk_bf16_f32 %0, %1, %2" : "=v"(r) : "v"(a), "v"(b));
  return r;
}
// exp2 via the trans pipe.
__device__ __forceinline__ float fast_exp2(float x) {
#if __has_builtin(__builtin_amdgcn_exp2f)
  return __builtin_amdgcn_exp2f(x);
#else
  float r;
  asm("v_exp_f32 %0, %1" : "=v"(r) : "v"(x));
  return r;
#endif
}
__device__ __forceinline__ f32x16 zero16() {
  f32x16 z;
#pragma unroll
  for (int i = 0; i < 16; ++i) z[i] = 0.f;
  return z;
}

} // namespace

// K0: pack weights transposed: wt[c*80 + o], o = [q0..7 | k0..7 | v0..63]
// Wq rows are pre-scaled by log2(e) so attn can use v_exp_f32 (exp2) directly.
__global__ void pack_weights(const float* __restrict__ Wq,
                             const float* __restrict__ Wk,
                             const float* __restrict__ Wv,
                             float* __restrict__ wt) {
  int idx = blockIdx.x * 256 + threadIdx.x;
  if (idx >= 64 * 80) return;
  int c = idx / 80, o = idx % 80;
  float v;
  if (o < 8)       v = Wq[o * 64 + c] * LOG2E;
  else if (o < 16) v = Wk[(o - 8) * 64 + c];
  else             v = Wv[(o - 16) * 64 + c];
  wt[idx] = v;
}

// K1a (R13 split): q+k only, 2048 blocks -> 8 blocks/CU fully co-resident
// (32 waves/CU vs 18 before) for max latency hiding on the x read.
// Body = R10/R12 chunk0 path (best measured form).
__global__ __launch_bounds__(256) void qk_kernel(
    const float* __restrict__ x, const float* __restrict__ wt,
    const float* __restrict__ bq, const float* __restrict__ bk,
    unsigned short* __restrict__ qh, unsigned short* __restrict__ ql,
    unsigned short* __restrict__ kh, unsigned short* __restrict__ kl) {
  size_t p = (size_t)blockIdx.x * 256 + threadIdx.x; // 0..524287
  int b = (int)(p >> 16);
  int rem = (int)(p & 65535);
  const float* xbase = x + (size_t)b * 64 * HWn + rem;

  float acc[16];
#pragma unroll
  for (int o = 0; o < 8; ++o) { acc[o] = bq[o] * LOG2E; acc[8 + o] = bk[o]; }

  float xa[8], xn[8];
#pragma unroll
  for (int cc = 0; cc < 8; ++cc) xa[cc] = xbase[(size_t)cc * HWn];

#pragma unroll 1
  for (int c0 = 0; c0 < 64; c0 += 16) {
#pragma unroll
    for (int cc = 0; cc < 8; ++cc) xn[cc] = xbase[(size_t)(c0 + 8 + cc) * HWn];
#pragma unroll
    for (int cc = 0; cc < 8; ++cc) {
      const float* w = wt + (c0 + cc) * 80; // wave-uniform -> s_load
      const float xc = xa[cc];
#pragma unroll
      for (int o = 0; o < 16; ++o) acc[o] = fmaf(xc, w[o], acc[o]);
    }
    const int cnx = (c0 + 16) & 63;
#pragma unroll
    for (int cc = 0; cc < 8; ++cc) xa[cc] = xbase[(size_t)(cnx + cc) * HWn];
#pragma unroll
    for (int cc = 0; cc < 8; ++cc) {
      const float* w = wt + (c0 + 8 + cc) * 80;
      const float xc = xn[cc];
#pragma unroll
      for (int o = 0; o < 16; ++o) acc[o] = fmaf(xc, w[o], acc[o]);
    }
  }

  unsigned dh[8], dl[8];
#pragma unroll
  for (int k = 0; k < 8; ++k) {
    float a0 = acc[2 * k], a1 = acc[2 * k + 1];
    unsigned h = cvt_pk_bf16(a0, a1);
    dl[k] = cvt_pk_bf16(a0 - fbits(h << 16), a1 - fbits(h & 0xffff0000u));
    dh[k] = h;
  }
  *(uint4*)(qh + p * 8) = make_uint4(dh[0], dh[1], dh[2], dh[3]);
  *(uint4*)(ql + p * 8) = make_uint4(dl[0], dl[1], dl[2], dl[3]);
  *(uint4*)(kh + p * 8) = make_uint4(dh[4], dh[5], dh[6], dh[7]);
  *(uint4*)(kl + p * 8) = make_uint4(dl[4], dl[5], dl[6], dl[7]);
}

// K1b (R13 split): v planes, 4 chunk-blocks per pixel-group with XCD-chunked
// remap (lin=(d&7)*1024+(d>>3)) so the 4 x-reads of one group L2-hit.
__global__ __launch_bounds__(256) void v_kernel(
    const float* __restrict__ x, const float* __restrict__ wt,
    const float* __restrict__ bv, unsigned short* __restrict__ vb) {
  const int d = blockIdx.x;                 // 0..8191
  const int lin = (d & 7) * 1024 + (d >> 3);
  const int chunk = lin & 3;                // 0..3
  size_t p = (size_t)(lin >> 2) * 256 + threadIdx.x; // 0..524287
  int b = (int)(p >> 16);
  int rem = (int)(p & 65535);
  const float* xbase = x + (size_t)b * 64 * HWn + rem;

  float acc[16];
#pragma unroll
  for (int o = 0; o < 16; ++o) acc[o] = bv[chunk * 16 + o];
  const int woff = 16 + chunk * 16;

  float xa[8], xn[8];
#pragma unroll
  for (int cc = 0; cc < 8; ++cc) xa[cc] = xbase[(size_t)cc * HWn];

#pragma unroll 1
  for (int c0 = 0; c0 < 64; c0 += 16) {
#pragma unroll
    for (int cc = 0; cc < 8; ++cc) xn[cc] = xbase[(size_t)(c0 + 8 + cc) * HWn];
#pragma unroll
    for (int cc = 0; cc < 8; ++cc) {
      const float* w = wt + (c0 + cc) * 80 + woff; // wave-uniform -> s_load
      const float xc = xa[cc];
#pragma unroll
      for (int o = 0; o < 16; ++o) acc[o] = fmaf(xc, w[o], acc[o]);
    }
    const int cnx = (c0 + 16) & 63;
#pragma unroll
    for (int cc = 0; cc < 8; ++cc) xa[cc] = xbase[(size_t)(cnx + cc) * HWn];
#pragma unroll
    for (int cc = 0; cc < 8; ++cc) {
      const float* w = wt + (c0 + 8 + cc) * 80 + woff;
      const float xc = xn[cc];
#pragma unroll
      for (int o = 0; o < 16; ++o) acc[o] = fmaf(xc, w[o], acc[o]);
    }
  }

  unsigned dv[8];
#pragma unroll
  for (int k = 0; k < 8; ++k) dv[k] = cvt_pk_bf16(acc[2 * k], acc[2 * k + 1]);
  unsigned short* vp = vb + (size_t)chunk * VPLANE + p * 16;
  *(uint4*)(vp + 0) = make_uint4(dv[0], dv[1], dv[2], dv[3]);
  *(uint4*)(vp + 8) = make_uint4(dv[4], dv[5], dv[6], dv[7]);
}

// K2: criss-cross attention slice via bf16 MFMA (split hi/lo for S accuracy).
//   S'[i,j] = log2e * sum_c Q[i,c]K[j,c]  (q pre-scaled; exp(S) == exp2(S'))
//   Z_i = sum_j exp2(S'[i,j]);  Out[c,j] = sum_i (V[c,i]/Z_i) * exp2(S'[i,j])
// R13: LDS 49->33KB (vz halved to 16KB; PV in two halves C1/D1/C2/D2 with the
// second v-batch prefetched during D1) -> 4 blocks/CU by LDS (was 3). raw_pre
// shrunk to 8 rounds (16 VGPR) to keep VGPR near 128 for the 4th block.
template <int MODE>
__global__ __launch_bounds__(256) void attn_kernel(
    const unsigned short* __restrict__ qh, const unsigned short* __restrict__ ql,
    const unsigned short* __restrict__ kh, const unsigned short* __restrict__ kl,
    const unsigned short* __restrict__ vb, _Float16* __restrict__ o) {
  const int s = (MODE == 1) ? (((blockIdx.x & 7) << 8) | (blockIdx.x >> 3))
                            : blockIdx.x;       // 0..2047 (bijective remap)
  const int t = threadIdx.x; // 0..255
  const int b = s >> 8;
  const int r = s & 255;     // h (row mode) or w (col mode)
  const int w = t >> 6;      // wave 0..3
  const int l = t & 63;      // lane
  const int g = l >> 5;      // lane half
  const int ln = l & 31;

  __shared__ short qs_h[256 * 8], qs_l[256 * 8]; // Q split bf16 [row][8]
  __shared__ short ks_h[256 * 8], ks_l[256 * 8]; // K split bf16
  __shared__ short vz[8192];                     // V*(1/Z) bf16 HALF-tile (16KB)
  __shared__ float Zl[256];                      // 1/Z

  float* Zp = (float*)vz; // Phase-B scratch: [8][256] partials (8 KB of 16 KB)

  size_t qkb, qk_stride;       // short-element offsets into qh/ql/kh/kl
  size_t v_pix_base, v_pix_stride; // PIXEL index into v planes
  if (MODE == 0) {
    qkb    = (size_t)s * (Ln * Cq);  qk_stride = Cq;
    v_pix_base = (size_t)s * Ln;     v_pix_stride = 1;
  } else {
    qkb    = ((size_t)b * HWn + r) * Cq;  qk_stride = (size_t)Ln * Cq;
    v_pix_base = (size_t)b * HWn + r;     v_pix_stride = Ln;
  }

  // ---- Phase C address algebra (hoisted; only rnd varies per round) ----
  const int rem_i = t >> 4;          // 0..15
  const int c4 = (t & 15) << 2;      // 0..60
  const int a_ = rem_i >> 3, g2 = (rem_i >> 2) & 1, t0 = rem_i & 3;
  const int e_ = 4 * a_ + t0;
  const int mt_ = c4 >> 5;
  const int lane_s0 = 32 * g2 + (c4 & 31);
  short* vz0 = &vz[(mt_ * 64 + lane_s0) * 8 + e_];
  const unsigned short* vp0 = vb + (size_t)(c4 >> 4) * VPLANE +
                              (v_pix_base + (size_t)rem_i * v_pix_stride) * 16 +
                              (c4 & 15);
  const size_t step = (size_t)256 * v_pix_stride; // shorts per round

  // ---- Phase A: stage pre-split Q,K rows + prefetch v rounds 0-7 ----
  {
    const size_t off = qkb + (size_t)t * qk_stride;
    *(bf16x8*)&qs_h[t * 8] = *(const bf16x8*)(qh + off);
    *(bf16x8*)&qs_l[t * 8] = *(const bf16x8*)(ql + off);
    *(bf16x8*)&ks_h[t * 8] = *(const bf16x8*)(kh + off);
    *(bf16x8*)&ks_l[t * 8] = *(const bf16x8*)(kl + off);
  }
  u16x4 raw_pre[8]; // 16 VGPRs, live across Phase B
#pragma unroll
  for (int rnd = 0; rnd < 8; ++rnd)
    raw_pre[rnd] = *(const u16x4*)(vp0 + rnd * step);
  __syncthreads();

  // ---- Phase B (sweep 1): St[j][i] tiles; per-(w,g) Z partials ----
  {
    const short* kb = g ? ks_l : ks_h;
    const int wg = (w << 1) | g; // 0..7
    bf16x8 afk0 = *(const bf16x8*)&kb[(ln + 32 * (2 * w + 0)) * 8];
    bf16x8 afk1 = *(const bf16x8*)&kb[(ln + 32 * (2 * w + 1)) * 8];
#pragma unroll 1
    for (int it = 0; it < 8; ++it) {
      int i = ln + 32 * it;
      bf16x8 bh = *(const bf16x8*)&qs_h[i * 8];
      bf16x8 bl = *(const bf16x8*)&qs_l[i * 8];
      float z0 = 0.f, z1 = 0.f, z2 = 0.f, z3 = 0.f; // break the add chain
      {
        f32x16 c = zero16();
        c = __builtin_amdgcn_mfma_f32_32x32x16_bf16(afk0, bh, c, 0, 0, 0);
        c = __builtin_amdgcn_mfma_f32_32x32x16_bf16(afk0, bl, c, 0, 0, 0);
#pragma unroll
        for (int rr = 0; rr < 16; ++rr) {
          float e = fast_exp2(c[rr]);
          if ((rr & 3) == 0) z0 += e; else if ((rr & 3) == 1) z1 += e;
          else if ((rr & 3) == 2) z2 += e; else z3 += e;
        }
      }
      {
        f32x16 c = zero16();
        c = __builtin_amdgcn_mfma_f32_32x32x16_bf16(afk1, bh, c, 0, 0, 0);
        c = __builtin_amdgcn_mfma_f32_32x32x16_bf16(afk1, bl, c, 0, 0, 0);
#pragma unroll
        for (int rr = 0; rr < 16; ++rr) {
          float e = fast_exp2(c[rr]);
          if ((rr & 3) == 0) z0 += e; else if ((rr & 3) == 1) z1 += e;
          else if ((rr & 3) == 2) z2 += e; else z3 += e;
        }
      }
      Zp[(wg << 8) + i] = (z0 + z1) + (z2 + z3);
    }
  }
  __syncthreads();
  {
    float z = 0.f;
#pragma unroll
    for (int k = 0; k < 8; ++k) z += Zp[(k << 8) + t];
    Zl[t] = 1.0f / z;
  }
  __syncthreads(); // Zl visible AND Zp reads done before vz overwrite

  // ---- Phase C1: scale v rounds 0-7 into vz; issue prefetch rounds 8-15 ----
#pragma unroll
  for (int rnd = 0; rnd < 8; ++rnd) {
    float iz = Zl[(rnd << 4) + rem_i];
#pragma unroll
    for (int u = 0; u < 4; ++u) {
      unsigned dd = cvt_pk_bf16(bf2f(raw_pre[rnd][u]) * iz, 0.f);
      vz0[rnd * 1024 + u * 8] = (short)dd; // low 16 bits
    }
  }
  u16x4 raw2[8];
#pragma unroll
  for (int rnd = 0; rnd < 8; ++rnd)
    raw2[rnd] = *(const u16x4*)(vp0 + (8 + rnd) * step);
  __syncthreads();

  // ---- Phase D: two PV half-sweeps over the 16KB vz ----
  f32x16 acc00 = zero16(), acc01 = zero16(), acc10 = zero16(), acc11 = zero16();
  bf16x8 bkh[2], bkl[2];
#pragma unroll
  for (int nt2 = 0; nt2 < 2; ++nt2) {
    int j = ln + 32 * (2 * w + nt2);
    bkh[nt2] = *(const bf16x8*)&ks_h[j * 8];
    bkl[nt2] = *(const bf16x8*)&ks_l[j * 8];
  }
  const short* qb = g ? qs_l : qs_h;

#pragma unroll
  for (int half = 0; half < 2; ++half) {
#pragma unroll 1
    for (int it = half * 4; it < half * 4 + 4; ++it) {
      int i = ln + 32 * it;
      bf16x8 aQ = *(const bf16x8*)&qb[i * 8];
      bf16x8 pf[2][2]; // [nt2][s2]
#pragma unroll
      for (int nt2 = 0; nt2 < 2; ++nt2) {
        f32x16 c = zero16();
        c = __builtin_amdgcn_mfma_f32_32x32x16_bf16(aQ, bkh[nt2], c, 0, 0, 0);
        c = __builtin_amdgcn_mfma_f32_32x32x16_bf16(aQ, bkl[nt2], c, 0, 0, 0);
        union { unsigned u[4]; bf16x8 v; } cv0, cv1;
#pragma unroll
        for (int k = 0; k < 4; ++k)
          cv0.u[k] = cvt_pk_bf16(fast_exp2(c[2 * k]), fast_exp2(c[2 * k + 1]));
#pragma unroll
        for (int k = 0; k < 4; ++k)
          cv1.u[k] = cvt_pk_bf16(fast_exp2(c[8 + 2 * k]), fast_exp2(c[8 + 2 * k + 1]));
        pf[nt2][0] = cv0.v;
        pf[nt2][1] = cv1.v;
      }
#pragma unroll
      for (int s2 = 0; s2 < 2; ++s2) {
#pragma unroll
        for (int mt = 0; mt < 2; ++mt) {
          bf16x8 vf = *(const bf16x8*)&vz[((((it & 3) * 2 + s2) * 2 + mt) * 64 + l) * 8];
          if (mt == 0) {
            acc00 = __builtin_amdgcn_mfma_f32_32x32x16_bf16(vf, pf[0][s2], acc00, 0, 0, 0);
            acc10 = __builtin_amdgcn_mfma_f32_32x32x16_bf16(vf, pf[1][s2], acc10, 0, 0, 0);
          } else {
            acc01 = __builtin_amdgcn_mfma_f32_32x32x16_bf16(vf, pf[0][s2], acc01, 0, 0, 0);
            acc11 = __builtin_amdgcn_mfma_f32_32x32x16_bf16(vf, pf[1][s2], acc11, 0, 0, 0);
          }
        }
      }
    }
    if (half == 0) {
      // refill vz with rounds 8-15 (raw2 already in flight)
      __syncthreads(); // D-half-1 reads done
#pragma unroll
      for (int rnd = 0; rnd < 8; ++rnd) {
        float iz = Zl[((rnd + 8) << 4) + rem_i];
#pragma unroll
        for (int u = 0; u < 4; ++u) {
          unsigned dd = cvt_pk_bf16(bf2f(raw2[rnd][u]) * iz, 0.f);
          vz0[rnd * 1024 + u * 8] = (short)dd;
        }
      }
      __syncthreads(); // vz half-2 ready
    }
  }

  // ---- Phase E: store C-layout accs as fp16 ----
  // row c = (reg&3) + 8*(reg>>2) + 4*g + 32*mt ; col j = ln + 32*(2w+nt2)
#pragma unroll
  for (int nt2 = 0; nt2 < 2; ++nt2) {
    int j = ln + 32 * (2 * w + nt2);
#pragma unroll
    for (int mt = 0; mt < 2; ++mt) {
      const f32x16& A = (nt2 == 0) ? (mt == 0 ? acc00 : acc01)
                                   : (mt == 0 ? acc10 : acc11);
#pragma unroll
      for (int reg = 0; reg < 16; ++reg) {
        int c = (reg & 3) + 8 * (reg >> 2) + 4 * g + 32 * mt;
        if (MODE == 0) {
          o[((size_t)b * 64 + c) * HWn + (size_t)r * 256 + j] = (_Float16)A[reg];
        } else {
          o[((size_t)s * 64 + c) * 256 + j] = (_Float16)A[reg];
        }
      }
    }
  }
}

// K3: out = gamma*(w_out + h_out^T) + x, fp16 intermediates.
// h-tile = 64 so each 64KB-strided ho row-read is a full 128B line (64 halves).
// LDS [256][66] halves: read addr bank = (t + rr/2)%32 -> 2-way (free).
__global__ __launch_bounds__(256) void merge_kernel(
    const _Float16* __restrict__ wo, const _Float16* __restrict__ ho,
    const float* __restrict__ x, const float* __restrict__ gamma,
    float* __restrict__ out) {
  const int h0 = blockIdx.x * 64;
  const int c = blockIdx.y;
  const int b = blockIdx.z;
  const int t = threadIdx.x;
  __shared__ _Float16 lds[256 * 66]; // [w][hh] padded (33.8 KB)

  const float g = gamma[0];

  // load ho[b][w=0..255][c][h0..h0+63]: 8 lanes cover one w-row (128B line)
#pragma unroll
  for (int it = 0; it < 8; ++it) {
    int e = it * 256 + t;       // 0..2047
    int w = e >> 3, q8 = (e & 7) << 3; // 8 halves (16B) per lane
    uint4 f = *(const uint4*)&ho[(((size_t)b * 256 + w) * 64 + c) * 256 + h0 + q8];
    unsigned* dst = (unsigned*)&lds[w * 66 + q8];
    dst[0] = f.x; dst[1] = f.y; dst[2] = f.z; dst[3] = f.w;
  }
  __syncthreads();

#pragma unroll 4
  for (int rr = 0; rr < 64; ++rr) {
    size_t idx = (((size_t)b * 64 + c) * 256 + h0 + rr) * 256 + t;
    out[idx] = g * ((float)wo[idx] + (float)lds[t * 66 + rr]) + x[idx];
  }
}

extern "C" void kernel_launch(void* const* d_in, const int* in_sizes, int n_in,
                              void* d_out, int out_size, void* d_ws, size_t ws_size,
                              hipStream_t stream) {
  const float* x     = (const float*)d_in[0];
  const float* Wq    = (const float*)d_in[1];
  const float* bq    = (const float*)d_in[2];
  const float* Wk    = (const float*)d_in[3];
  const float* bk    = (const float*)d_in[4];
  const float* Wv    = (const float*)d_in[5];
  const float* bv    = (const float*)d_in[6];
  const float* gamma = (const float*)d_in[7];
  float* out = (float*)d_out;
  char*  ws  = (char*)d_ws;

  float*          wt = (float*)(ws + WT_B);
  unsigned short* qh = (unsigned short*)(ws + QH_B);
  unsigned short* ql = (unsigned short*)(ws + QL_B);
  unsigned short* kh = (unsigned short*)(ws + KH_B);
  unsigned short* kl = (unsigned short*)(ws + KL_B);
  unsigned short* vb = (unsigned short*)(ws + VB_B);
  _Float16*       ho = (_Float16*)(ws + HO_B);
  _Float16*       wo = (_Float16*)(ws + WO_B);

  hipLaunchKernelGGL(pack_weights, dim3(20), dim3(256), 0, stream, Wq, Wk, Wv, wt);
  hipLaunchKernelGGL(qk_kernel, dim3(2048), dim3(256), 0, stream,
                     x, wt, bq, bk, qh, ql, kh, kl);
  hipLaunchKernelGGL(v_kernel, dim3(8192), dim3(256), 0, stream,
                     x, wt, bv, vb);
  hipLaunchKernelGGL((attn_kernel<0>), dim3(2048), dim3(256), 0, stream,
                     qh, ql, kh, kl, vb, wo);  // row pass -> w_out fp16
  hipLaunchKernelGGL((attn_kernel<1>), dim3(2048), dim3(256), 0, stream,
                     qh, ql, kh, kl, vb, ho);  // col pass -> h_out fp16
  hipLaunchKernelGGL(merge_kernel, dim3(4, 64, 8), dim3(256), 0, stream,
                     wo, ho, x, gamma, out);
}

// Round 14
// 476.658 us; speedup vs baseline: 1.0062x; 1.0062x over previous
//
#include <hip/hip_runtime.h>
#include <cstddef>

namespace {

constexpr int    Bn   = 8;
constexpr int    Cc   = 64;    // value channels
constexpr int    Cq   = 8;     // q/k channels
constexpr int    Ln   = 256;   // H == W
constexpr size_t HWn  = 65536; // H*W
constexpr size_t NPIX = (size_t)Bn * HWn; // 524288
constexpr size_t VPLANE = NPIX * 16;      // shorts per v chunk-plane

constexpr float LOG2E = 1.44269504088896f;

// workspace layout (byte offsets)
constexpr size_t WT_B = 0;                        // 80*64 fp32 weights (20 KB)
constexpr size_t QH_B = 32768;                    // NPIX*8 bf16 (8 MB)
constexpr size_t QL_B = QH_B + NPIX * 8 * 2;
constexpr size_t KH_B = QL_B + NPIX * 8 * 2;
constexpr size_t KL_B = KH_B + NPIX * 8 * 2;
constexpr size_t VB_B = KL_B + NPIX * 8 * 2;      // 4 planes x NPIX*16 bf16 (64 MB)
constexpr size_t HO_B = VB_B + NPIX * 64 * 2;     // NPIX*64 fp16 h_out (64 MB)
constexpr size_t WO_B = HO_B + NPIX * 64 * 2;     // NPIX*64 fp16 w_out (64 MB)
// total ~224 MB

typedef short bf16x8 __attribute__((ext_vector_type(8)));  // 8 bf16 (4 VGPRs)
typedef float f32x16 __attribute__((ext_vector_type(16))); // MFMA 32x32 C/D
typedef unsigned short u16x4 __attribute__((ext_vector_type(4)));

__device__ __forceinline__ float bf2f(unsigned short h) {
  union { unsigned u; float f; } c; c.u = ((unsigned)h) << 16;
  return c.f;
}
__device__ __forceinline__ float fbits(unsigned u) {
  union { unsigned u; float f; } c; c.u = u; return c.f;
}
// packed f32->bf16 RNE via HW (same rounding as the old hand-rolled f2bf):
// dst low16 = cvt(a), high16 = cvt(b)
__device__ __forceinline__ unsigned cvt_pk_bf16(float a, float b) {
  unsigned r;
  asm("v_cvt_pk_bf16_f32 %0, %1, %2" : "=v"(r) : "v"(a), "v"(b));
  return r;
}
// exp2 via the trans pipe.
__device__ __forceinline__ float fast_exp2(float x) {
#if __has_builtin(__builtin_amdgcn_exp2f)
  return __builtin_amdgcn_exp2f(x);
#else
  float r;
  asm("v_exp_f32 %0, %1" : "=v"(r) : "v"(x));
  return r;
#endif
}
__device__ __forceinline__ f32x16 zero16() {
  f32x16 z;
#pragma unroll
  for (int i = 0; i < 16; ++i) z[i] = 0.f;
  return z;
}

} // namespace

// K0: pack weights transposed: wt[c*80 + o], o = [q0..7 | k0..7 | v0..63]
// Wq rows are pre-scaled by log2(e) so attn can use v_exp_f32 (exp2) directly.
__global__ void pack_weights(const float* __restrict__ Wq,
                             const float* __restrict__ Wk,
                             const float* __restrict__ Wv,
                             float* __restrict__ wt) {
  int idx = blockIdx.x * 256 + threadIdx.x;
  if (idx >= 64 * 80) return;
  int c = idx / 80, o = idx % 80;
  float v;
  if (o < 8)       v = Wq[o * 64 + c] * LOG2E;
  else if (o < 16) v = Wk[(o - 8) * 64 + c];
  else             v = Wv[(o - 16) * 64 + c];
  wt[idx] = v;
}

// K1a: q+k only, 2048 blocks (8 blocks/CU co-resident).
__global__ __launch_bounds__(256) void qk_kernel(
    const float* __restrict__ x, const float* __restrict__ wt,
    const float* __restrict__ bq, const float* __restrict__ bk,
    unsigned short* __restrict__ qh, unsigned short* __restrict__ ql,
    unsigned short* __restrict__ kh, unsigned short* __restrict__ kl) {
  size_t p = (size_t)blockIdx.x * 256 + threadIdx.x; // 0..524287
  int b = (int)(p >> 16);
  int rem = (int)(p & 65535);
  const float* xbase = x + (size_t)b * 64 * HWn + rem;

  float acc[16];
#pragma unroll
  for (int o = 0; o < 8; ++o) { acc[o] = bq[o] * LOG2E; acc[8 + o] = bk[o]; }

  float xa[8], xn[8];
#pragma unroll
  for (int cc = 0; cc < 8; ++cc) xa[cc] = xbase[(size_t)cc * HWn];

#pragma unroll 1
  for (int c0 = 0; c0 < 64; c0 += 16) {
#pragma unroll
    for (int cc = 0; cc < 8; ++cc) xn[cc] = xbase[(size_t)(c0 + 8 + cc) * HWn];
#pragma unroll
    for (int cc = 0; cc < 8; ++cc) {
      const float* w = wt + (c0 + cc) * 80; // wave-uniform -> s_load
      const float xc = xa[cc];
#pragma unroll
      for (int o = 0; o < 16; ++o) acc[o] = fmaf(xc, w[o], acc[o]);
    }
    const int cnx = (c0 + 16) & 63;
#pragma unroll
    for (int cc = 0; cc < 8; ++cc) xa[cc] = xbase[(size_t)(cnx + cc) * HWn];
#pragma unroll
    for (int cc = 0; cc < 8; ++cc) {
      const float* w = wt + (c0 + 8 + cc) * 80;
      const float xc = xn[cc];
#pragma unroll
      for (int o = 0; o < 16; ++o) acc[o] = fmaf(xc, w[o], acc[o]);
    }
  }

  unsigned dh[8], dl[8];
#pragma unroll
  for (int k = 0; k < 8; ++k) {
    float a0 = acc[2 * k], a1 = acc[2 * k + 1];
    unsigned h = cvt_pk_bf16(a0, a1);
    dl[k] = cvt_pk_bf16(a0 - fbits(h << 16), a1 - fbits(h & 0xffff0000u));
    dh[k] = h;
  }
  *(uint4*)(qh + p * 8) = make_uint4(dh[0], dh[1], dh[2], dh[3]);
  *(uint4*)(ql + p * 8) = make_uint4(dl[0], dl[1], dl[2], dl[3]);
  *(uint4*)(kh + p * 8) = make_uint4(dh[4], dh[5], dh[6], dh[7]);
  *(uint4*)(kl + p * 8) = make_uint4(dl[4], dl[5], dl[6], dl[7]);
}

// K1b: v planes, 4 chunk-blocks per pixel-group with XCD-chunked remap.
__global__ __launch_bounds__(256) void v_kernel(
    const float* __restrict__ x, const float* __restrict__ wt,
    const float* __restrict__ bv, unsigned short* __restrict__ vb) {
  const int d = blockIdx.x;                 // 0..8191
  const int lin = (d & 7) * 1024 + (d >> 3);
  const int chunk = lin & 3;                // 0..3
  size_t p = (size_t)(lin >> 2) * 256 + threadIdx.x; // 0..524287
  int b = (int)(p >> 16);
  int rem = (int)(p & 65535);
  const float* xbase = x + (size_t)b * 64 * HWn + rem;

  float acc[16];
#pragma unroll
  for (int o = 0; o < 16; ++o) acc[o] = bv[chunk * 16 + o];
  const int woff = 16 + chunk * 16;

  float xa[8], xn[8];
#pragma unroll
  for (int cc = 0; cc < 8; ++cc) xa[cc] = xbase[(size_t)cc * HWn];

#pragma unroll 1
  for (int c0 = 0; c0 < 64; c0 += 16) {
#pragma unroll
    for (int cc = 0; cc < 8; ++cc) xn[cc] = xbase[(size_t)(c0 + 8 + cc) * HWn];
#pragma unroll
    for (int cc = 0; cc < 8; ++cc) {
      const float* w = wt + (c0 + cc) * 80 + woff; // wave-uniform -> s_load
      const float xc = xa[cc];
#pragma unroll
      for (int o = 0; o < 16; ++o) acc[o] = fmaf(xc, w[o], acc[o]);
    }
    const int cnx = (c0 + 16) & 63;
#pragma unroll
    for (int cc = 0; cc < 8; ++cc) xa[cc] = xbase[(size_t)(cnx + cc) * HWn];
#pragma unroll
    for (int cc = 0; cc < 8; ++cc) {
      const float* w = wt + (c0 + 8 + cc) * 80 + woff;
      const float xc = xn[cc];
#pragma unroll
      for (int o = 0; o < 16; ++o) acc[o] = fmaf(xc, w[o], acc[o]);
    }
  }

  unsigned dv[8];
#pragma unroll
  for (int k = 0; k < 8; ++k) dv[k] = cvt_pk_bf16(acc[2 * k], acc[2 * k + 1]);
  unsigned short* vp = vb + (size_t)chunk * VPLANE + p * 16;
  *(uint4*)(vp + 0) = make_uint4(dv[0], dv[1], dv[2], dv[3]);
  *(uint4*)(vp + 8) = make_uint4(dv[4], dv[5], dv[6], dv[7]);
}

// K2: criss-cross attention slice via bf16 MFMA (split hi/lo for S accuracy).
// R14: vz XOR-swizzle (T2). R13 PMC: SQ_LDS_BANK_CONFLICT=7.34M == Phase-C
// ds_write_b16 16-way conflicts (64 lanes -> 4 banks). Fix: logical byte addr
// L gets physical L ^ (((L>>7)&7)<<4) on BOTH write and read. Write key
// (g2<<2)|((t&7)>>1) is thread-const (u can't carry into bits 9:7); read key
// (l>>3)&7 -> lsw = l ^ ((l>>3)&7), a bijection, reads stay conflict-free.
// Writes: 4 -> 16 distinct banks (residual 4-way; m136: 1.58x, cheap).
template <int MODE>
__global__ __launch_bounds__(256) void attn_kernel(
    const unsigned short* __restrict__ qh, const unsigned short* __restrict__ ql,
    const unsigned short* __restrict__ kh, const unsigned short* __restrict__ kl,
    const unsigned short* __restrict__ vb, _Float16* __restrict__ o) {
  const int s = (MODE == 1) ? (((blockIdx.x & 7) << 8) | (blockIdx.x >> 3))
                            : blockIdx.x;       // 0..2047 (bijective remap)
  const int t = threadIdx.x; // 0..255
  const int b = s >> 8;
  const int r = s & 255;     // h (row mode) or w (col mode)
  const int w = t >> 6;      // wave 0..3
  const int l = t & 63;      // lane
  const int g = l >> 5;      // lane half
  const int ln = l & 31;

  __shared__ short qs_h[256 * 8], qs_l[256 * 8]; // Q split bf16 [row][8]
  __shared__ short ks_h[256 * 8], ks_l[256 * 8]; // K split bf16
  __shared__ short vz[8192];                     // V*(1/Z) bf16 HALF-tile (16KB)
  __shared__ float Zl[256];                      // 1/Z

  float* Zp = (float*)vz; // Phase-B scratch: [8][256] partials (8 KB of 16 KB)

  size_t qkb, qk_stride;       // short-element offsets into qh/ql/kh/kl
  size_t v_pix_base, v_pix_stride; // PIXEL index into v planes
  if (MODE == 0) {
    qkb    = (size_t)s * (Ln * Cq);  qk_stride = Cq;
    v_pix_base = (size_t)s * Ln;     v_pix_stride = 1;
  } else {
    qkb    = ((size_t)b * HWn + r) * Cq;  qk_stride = (size_t)Ln * Cq;
    v_pix_base = (size_t)b * HWn + r;     v_pix_stride = Ln;
  }

  // ---- Phase C address algebra (hoisted; only rnd varies per round) ----
  const int rem_i = t >> 4;          // 0..15
  const int c4 = (t & 15) << 2;      // 0..60
  const int a_ = rem_i >> 3, g2 = (rem_i >> 2) & 1, t0 = rem_i & 3;
  const int e_ = 4 * a_ + t0;
  const int mt_ = c4 >> 5;
  const int lane_s0 = 32 * g2 + (c4 & 31);
  // swizzled write base (bytes), rnd=0,u=0; key = logical bits[9:7]
  const unsigned key_w = (unsigned)((g2 << 2) | ((t & 7) >> 1));
  const unsigned wbase = ((unsigned)(((mt_ * 64 + lane_s0) * 8 + e_) * 2)) ^ (key_w << 4);
  char* vzb = (char*)vz;
  const unsigned short* vp0 = vb + (size_t)(c4 >> 4) * VPLANE +
                              (v_pix_base + (size_t)rem_i * v_pix_stride) * 16 +
                              (c4 & 15);
  const size_t step = (size_t)256 * v_pix_stride; // shorts per round
  // swizzled read lane slot (key_r = (l>>3)&7)
  const int lsw = l ^ ((l >> 3) & 7);

  // ---- Phase A: stage pre-split Q,K rows + prefetch v rounds 0-7 ----
  {
    const size_t off = qkb + (size_t)t * qk_stride;
    *(bf16x8*)&qs_h[t * 8] = *(const bf16x8*)(qh + off);
    *(bf16x8*)&qs_l[t * 8] = *(const bf16x8*)(ql + off);
    *(bf16x8*)&ks_h[t * 8] = *(const bf16x8*)(kh + off);
    *(bf16x8*)&ks_l[t * 8] = *(const bf16x8*)(kl + off);
  }
  u16x4 raw_pre[8]; // 16 VGPRs, live across Phase B
#pragma unroll
  for (int rnd = 0; rnd < 8; ++rnd)
    raw_pre[rnd] = *(const u16x4*)(vp0 + rnd * step);
  __syncthreads();

  // ---- Phase B (sweep 1): St[j][i] tiles; per-(w,g) Z partials ----
  {
    const short* kb = g ? ks_l : ks_h;
    const int wg = (w << 1) | g; // 0..7
    bf16x8 afk0 = *(const bf16x8*)&kb[(ln + 32 * (2 * w + 0)) * 8];
    bf16x8 afk1 = *(const bf16x8*)&kb[(ln + 32 * (2 * w + 1)) * 8];
#pragma unroll 1
    for (int it = 0; it < 8; ++it) {
      int i = ln + 32 * it;
      bf16x8 bh = *(const bf16x8*)&qs_h[i * 8];
      bf16x8 bl = *(const bf16x8*)&qs_l[i * 8];
      float z0 = 0.f, z1 = 0.f, z2 = 0.f, z3 = 0.f; // break the add chain
      {
        f32x16 c = zero16();
        c = __builtin_amdgcn_mfma_f32_32x32x16_bf16(afk0, bh, c, 0, 0, 0);
        c = __builtin_amdgcn_mfma_f32_32x32x16_bf16(afk0, bl, c, 0, 0, 0);
#pragma unroll
        for (int rr = 0; rr < 16; ++rr) {
          float e = fast_exp2(c[rr]);
          if ((rr & 3) == 0) z0 += e; else if ((rr & 3) == 1) z1 += e;
          else if ((rr & 3) == 2) z2 += e; else z3 += e;
        }
      }
      {
        f32x16 c = zero16();
        c = __builtin_amdgcn_mfma_f32_32x32x16_bf16(afk1, bh, c, 0, 0, 0);
        c = __builtin_amdgcn_mfma_f32_32x32x16_bf16(afk1, bl, c, 0, 0, 0);
#pragma unroll
        for (int rr = 0; rr < 16; ++rr) {
          float e = fast_exp2(c[rr]);
          if ((rr & 3) == 0) z0 += e; else if ((rr & 3) == 1) z1 += e;
          else if ((rr & 3) == 2) z2 += e; else z3 += e;
        }
      }
      Zp[(wg << 8) + i] = (z0 + z1) + (z2 + z3);
    }
  }
  __syncthreads();
  {
    float z = 0.f;
#pragma unroll
    for (int k = 0; k < 8; ++k) z += Zp[(k << 8) + t];
    Zl[t] = 1.0f / z;
  }
  __syncthreads(); // Zl visible AND Zp reads done before vz overwrite

  // ---- Phase C1: scale v rounds 0-7 into vz (swizzled); prefetch 8-15 ----
#pragma unroll
  for (int rnd = 0; rnd < 8; ++rnd) {
    float iz = Zl[(rnd << 4) + rem_i];
#pragma unroll
    for (int u = 0; u < 4; ++u) {
      unsigned dd = cvt_pk_bf16(bf2f(raw_pre[rnd][u]) * iz, 0.f);
      *(short*)(vzb + ((wbase ^ (unsigned)(u << 4)) + rnd * 2048)) = (short)dd;
    }
  }
  u16x4 raw2[8];
#pragma unroll
  for (int rnd = 0; rnd < 8; ++rnd)
    raw2[rnd] = *(const u16x4*)(vp0 + (8 + rnd) * step);
  __syncthreads();

  // ---- Phase D: two PV half-sweeps over the 16KB vz ----
  f32x16 acc00 = zero16(), acc01 = zero16(), acc10 = zero16(), acc11 = zero16();
  bf16x8 bkh[2], bkl[2];
#pragma unroll
  for (int nt2 = 0; nt2 < 2; ++nt2) {
    int j = ln + 32 * (2 * w + nt2);
    bkh[nt2] = *(const bf16x8*)&ks_h[j * 8];
    bkl[nt2] = *(const bf16x8*)&ks_l[j * 8];
  }
  const short* qb = g ? qs_l : qs_h;

#pragma unroll
  for (int half = 0; half < 2; ++half) {
#pragma unroll 1
    for (int it = half * 4; it < half * 4 + 4; ++it) {
      int i = ln + 32 * it;
      bf16x8 aQ = *(const bf16x8*)&qb[i * 8];
      bf16x8 pf[2][2]; // [nt2][s2]
#pragma unroll
      for (int nt2 = 0; nt2 < 2; ++nt2) {
        f32x16 c = zero16();
        c = __builtin_amdgcn_mfma_f32_32x32x16_bf16(aQ, bkh[nt2], c, 0, 0, 0);
        c = __builtin_amdgcn_mfma_f32_32x32x16_bf16(aQ, bkl[nt2], c, 0, 0, 0);
        union { unsigned u[4]; bf16x8 v; } cv0, cv1;
#pragma unroll
        for (int k = 0; k < 4; ++k)
          cv0.u[k] = cvt_pk_bf16(fast_exp2(c[2 * k]), fast_exp2(c[2 * k + 1]));
#pragma unroll
        for (int k = 0; k < 4; ++k)
          cv1.u[k] = cvt_pk_bf16(fast_exp2(c[8 + 2 * k]), fast_exp2(c[8 + 2 * k + 1]));
        pf[nt2][0] = cv0.v;
        pf[nt2][1] = cv1.v;
      }
#pragma unroll
      for (int s2 = 0; s2 < 2; ++s2) {
#pragma unroll
        for (int mt = 0; mt < 2; ++mt) {
          bf16x8 vf = *(const bf16x8*)&vz[((((it & 3) * 2 + s2) * 2 + mt) * 64 + lsw) * 8];
          if (mt == 0) {
            acc00 = __builtin_amdgcn_mfma_f32_32x32x16_bf16(vf, pf[0][s2], acc00, 0, 0, 0);
            acc10 = __builtin_amdgcn_mfma_f32_32x32x16_bf16(vf, pf[1][s2], acc10, 0, 0, 0);
          } else {
            acc01 = __builtin_amdgcn_mfma_f32_32x32x16_bf16(vf, pf[0][s2], acc01, 0, 0, 0);
            acc11 = __builtin_amdgcn_mfma_f32_32x32x16_bf16(vf, pf[1][s2], acc11, 0, 0, 0);
          }
        }
      }
    }
    if (half == 0) {
      // refill vz with rounds 8-15 (raw2 already in flight)
      __syncthreads(); // D-half-1 reads done
#pragma unroll
      for (int rnd = 0; rnd < 8; ++rnd) {
        float iz = Zl[((rnd + 8) << 4) + rem_i];
#pragma unroll
        for (int u = 0; u < 4; ++u) {
          unsigned dd = cvt_pk_bf16(bf2f(raw2[rnd][u]) * iz, 0.f);
          *(short*)(vzb + ((wbase ^ (unsigned)(u << 4)) + rnd * 2048)) = (short)dd;
        }
      }
      __syncthreads(); // vz half-2 ready
    }
  }

  // ---- Phase E: store C-layout accs as fp16 ----
  // row c = (reg&3) + 8*(reg>>2) + 4*g + 32*mt ; col j = ln + 32*(2w+nt2)
#pragma unroll
  for (int nt2 = 0; nt2 < 2; ++nt2) {
    int j = ln + 32 * (2 * w + nt2);
#pragma unroll
    for (int mt = 0; mt < 2; ++mt) {
      const f32x16& A = (nt2 == 0) ? (mt == 0 ? acc00 : acc01)
                                   : (mt == 0 ? acc10 : acc11);
#pragma unroll
      for (int reg = 0; reg < 16; ++reg) {
        int c = (reg & 3) + 8 * (reg >> 2) + 4 * g + 32 * mt;
        if (MODE == 0) {
          o[((size_t)b * 64 + c) * HWn + (size_t)r * 256 + j] = (_Float16)A[reg];
        } else {
          o[((size_t)s * 64 + c) * 256 + j] = (_Float16)A[reg];
        }
      }
    }
  }
}

// K3: out = gamma*(w_out + h_out^T) + x, fp16 intermediates.
// h-tile = 64 so each 64KB-strided ho row-read is a full 128B line (64 halves).
// LDS [256][66] halves: read addr bank = (t + rr/2)%32 -> 2-way (free).
__global__ __launch_bounds__(256) void merge_kernel(
    const _Float16* __restrict__ wo, const _Float16* __restrict__ ho,
    const float* __restrict__ x, const float* __restrict__ gamma,
    float* __restrict__ out) {
  const int h0 = blockIdx.x * 64;
  const int c = blockIdx.y;
  const int b = blockIdx.z;
  const int t = threadIdx.x;
  __shared__ _Float16 lds[256 * 66]; // [w][hh] padded (33.8 KB)

  const float g = gamma[0];

  // load ho[b][w=0..255][c][h0..h0+63]: 8 lanes cover one w-row (128B line)
#pragma unroll
  for (int it = 0; it < 8; ++it) {
    int e = it * 256 + t;       // 0..2047
    int w = e >> 3, q8 = (e & 7) << 3; // 8 halves (16B) per lane
    uint4 f = *(const uint4*)&ho[(((size_t)b * 256 + w) * 64 + c) * 256 + h0 + q8];
    unsigned* dst = (unsigned*)&lds[w * 66 + q8];
    dst[0] = f.x; dst[1] = f.y; dst[2] = f.z; dst[3] = f.w;
  }
  __syncthreads();

#pragma unroll 4
  for (int rr = 0; rr < 64; ++rr) {
    size_t idx = (((size_t)b * 64 + c) * 256 + h0 + rr) * 256 + t;
    out[idx] = g * ((float)wo[idx] + (float)lds[t * 66 + rr]) + x[idx];
  }
}

extern "C" void kernel_launch(void* const* d_in, const int* in_sizes, int n_in,
                              void* d_out, int out_size, void* d_ws, size_t ws_size,
                              hipStream_t stream) {
  const float* x     = (const float*)d_in[0];
  const float* Wq    = (const float*)d_in[1];
  const float* bq    = (const float*)d_in[2];
  const float* Wk    = (const float*)d_in[3];
  const float* bk    = (const float*)d_in[4];
  const float* Wv    = (const float*)d_in[5];
  const float* bv    = (const float*)d_in[6];
  const float* gamma = (const float*)d_in[7];
  float* out = (float*)d_out;
  char*  ws  = (char*)d_ws;

  float*          wt = (float*)(ws + WT_B);
  unsigned short* qh = (unsigned short*)(ws + QH_B);
  unsigned short* ql = (unsigned short*)(ws + QL_B);
  unsigned short* kh = (unsigned short*)(ws + KH_B);
  unsigned short* kl = (unsigned short*)(ws + KL_B);
  unsigned short* vb = (unsigned short*)(ws + VB_B);
  _Float16*       ho = (_Float16*)(ws + HO_B);
  _Float16*       wo = (_Float16*)(ws + WO_B);

  hipLaunchKernelGGL(pack_weights, dim3(20), dim3(256), 0, stream, Wq, Wk, Wv, wt);
  hipLaunchKernelGGL(qk_kernel, dim3(2048), dim3(256), 0, stream,
                     x, wt, bq, bk, qh, ql, kh, kl);
  hipLaunchKernelGGL(v_kernel, dim3(8192), dim3(256), 0, stream,
                     x, wt, bv, vb);
  hipLaunchKernelGGL((attn_kernel<0>), dim3(2048), dim3(256), 0, stream,
                     qh, ql, kh, kl, vb, wo);  // row pass -> w_out fp16
  hipLaunchKernelGGL((attn_kernel<1>), dim3(2048), dim3(256), 0, stream,
                     qh, ql, kh, kl, vb, ho);  // col pass -> h_out fp16
  hipLaunchKernelGGL(merge_kernel, dim3(4, 64, 8), dim3(256), 0, stream,
                     wo, ho, x, gamma, out);
}

// Round 15
// 451.664 us; speedup vs baseline: 1.0618x; 1.0553x over previous
//
#include <hip/hip_runtime.h>
#include <cstddef>

namespace {

constexpr int    Bn   = 8;
constexpr int    Cc   = 64;    // value channels
constexpr int    Cq   = 8;     // q/k channels
constexpr int    Ln   = 256;   // H == W
constexpr size_t HWn  = 65536; // H*W
constexpr size_t NPIX = (size_t)Bn * HWn; // 524288
constexpr size_t VPLANE = NPIX * 16;      // shorts per v chunk-plane

constexpr float LOG2E = 1.44269504088896f;

// workspace layout (byte offsets)
constexpr size_t WT_B = 0;                        // 80*64 fp32 weights (20 KB)
constexpr size_t QH_B = 32768;                    // NPIX*8 bf16 (8 MB)
constexpr size_t QL_B = QH_B + NPIX * 8 * 2;
constexpr size_t KH_B = QL_B + NPIX * 8 * 2;
constexpr size_t KL_B = KH_B + NPIX * 8 * 2;
constexpr size_t VB_B = KL_B + NPIX * 8 * 2;      // 4 planes x NPIX*16 bf16 (64 MB)
constexpr size_t HO_B = VB_B + NPIX * 64 * 2;     // NPIX*64 fp16 h_out (64 MB)
constexpr size_t WO_B = HO_B + NPIX * 64 * 2;     // NPIX*64 fp16 w_out (64 MB)
// total ~224 MB

typedef short bf16x8 __attribute__((ext_vector_type(8)));  // 8 bf16 (4 VGPRs)
typedef float f32x16 __attribute__((ext_vector_type(16))); // MFMA 32x32 C/D
typedef unsigned short u16x4 __attribute__((ext_vector_type(4)));

__device__ __forceinline__ float bf2f(unsigned short h) {
  union { unsigned u; float f; } c; c.u = ((unsigned)h) << 16;
  return c.f;
}
__device__ __forceinline__ float fbits(unsigned u) {
  union { unsigned u; float f; } c; c.u = u; return c.f;
}
// packed f32->bf16 RNE via HW (same rounding as the old hand-rolled f2bf):
// dst low16 = cvt(a), high16 = cvt(b)
__device__ __forceinline__ unsigned cvt_pk_bf16(float a, float b) {
  unsigned r;
  asm("v_cvt_pk_bf16_f32 %0, %1, %2" : "=v"(r) : "v"(a), "v"(b));
  return r;
}
// exp2 via the trans pipe.
__device__ __forceinline__ float fast_exp2(float x) {
#if __has_builtin(__builtin_amdgcn_exp2f)
  return __builtin_amdgcn_exp2f(x);
#else
  float r;
  asm("v_exp_f32 %0, %1" : "=v"(r) : "v"(x));
  return r;
#endif
}
__device__ __forceinline__ f32x16 zero16() {
  f32x16 z;
#pragma unroll
  for (int i = 0; i < 16; ++i) z[i] = 0.f;
  return z;
}

} // namespace

// K0: pack weights transposed: wt[c*80 + o], o = [q0..7 | k0..7 | v0..63]
// Wq rows are pre-scaled by log2(e) so attn can use v_exp_f32 (exp2) directly.
__global__ void pack_weights(const float* __restrict__ Wq,
                             const float* __restrict__ Wk,
                             const float* __restrict__ Wv,
                             float* __restrict__ wt) {
  int idx = blockIdx.x * 256 + threadIdx.x;
  if (idx >= 64 * 80) return;
  int c = idx / 80, o = idx % 80;
  float v;
  if (o < 8)       v = Wq[o * 64 + c] * LOG2E;
  else if (o < 16) v = Wk[(o - 8) * 64 + c];
  else             v = Wv[(o - 16) * 64 + c];
  wt[idx] = v;
}

// K1: per-pixel 1x1 convs — EXACT R12/R10 combined form (best measured:
// 100.4us, VALU 48%, FETCH 66MB). R13/R14's qk/v split cost ~10us net (extra
// dispatch boundary + lost 5-chunk adjacency) -> recombined.
__global__ __launch_bounds__(256) void qkv_kernel(
    const float* __restrict__ x, const float* __restrict__ wt,
    const float* __restrict__ bq, const float* __restrict__ bk,
    const float* __restrict__ bv,
    unsigned short* __restrict__ qh, unsigned short* __restrict__ ql,
    unsigned short* __restrict__ kh, unsigned short* __restrict__ kl,
    unsigned short* __restrict__ vb) {
  const int d = blockIdx.x;                 // 0..10239
  const int lin = (d & 7) * 1280 + (d >> 3);
  const int chunk = lin % 5;                // 0..4
  size_t p = (size_t)(lin / 5) * 256 + threadIdx.x; // 0..524287
  int b = (int)(p >> 16);
  int rem = (int)(p & 65535);
  const float* xbase = x + (size_t)b * 64 * HWn + rem;

  float acc[16];
  if (chunk == 0) {
#pragma unroll
    for (int o = 0; o < 8; ++o) { acc[o] = bq[o] * LOG2E; acc[8 + o] = bk[o]; }
  } else {
#pragma unroll
    for (int o = 0; o < 16; ++o) acc[o] = bv[(chunk - 1) * 16 + o];
  }
  const int woff = (chunk == 0) ? 0 : 16 + (chunk - 1) * 16;

  float xa[8], xn[8];
#pragma unroll
  for (int cc = 0; cc < 8; ++cc) xa[cc] = xbase[(size_t)cc * HWn];

#pragma unroll 1
  for (int c0 = 0; c0 < 64; c0 += 16) {
    // issue next batch while FMAs run on current
#pragma unroll
    for (int cc = 0; cc < 8; ++cc) xn[cc] = xbase[(size_t)(c0 + 8 + cc) * HWn];
#pragma unroll
    for (int cc = 0; cc < 8; ++cc) {
      const float* w = wt + (c0 + cc) * 80 + woff; // wave-uniform -> s_load
      const float xc = xa[cc];
#pragma unroll
      for (int o = 0; o < 16; ++o) acc[o] = fmaf(xc, w[o], acc[o]);
    }
    const int cnx = (c0 + 16) & 63; // last iter wraps to 0 (harmless L2 hits)
#pragma unroll
    for (int cc = 0; cc < 8; ++cc) xa[cc] = xbase[(size_t)(cnx + cc) * HWn];
#pragma unroll
    for (int cc = 0; cc < 8; ++cc) {
      const float* w = wt + (c0 + 8 + cc) * 80 + woff;
      const float xc = xn[cc];
#pragma unroll
      for (int o = 0; o < 16; ++o) acc[o] = fmaf(xc, w[o], acc[o]);
    }
  }

  if (chunk == 0) {
    // q = acc[0..7], k = acc[8..15]: split hi/lo bf16 via cvt_pk
    unsigned dh[8], dl[8];
#pragma unroll
    for (int k = 0; k < 8; ++k) {
      float a0 = acc[2 * k], a1 = acc[2 * k + 1];
      unsigned h = cvt_pk_bf16(a0, a1);
      dl[k] = cvt_pk_bf16(a0 - fbits(h << 16), a1 - fbits(h & 0xffff0000u));
      dh[k] = h;
    }
    *(uint4*)(qh + p * 8) = make_uint4(dh[0], dh[1], dh[2], dh[3]);
    *(uint4*)(ql + p * 8) = make_uint4(dl[0], dl[1], dl[2], dl[3]);
    *(uint4*)(kh + p * 8) = make_uint4(dh[4], dh[5], dh[6], dh[7]);
    *(uint4*)(kl + p * 8) = make_uint4(dl[4], dl[5], dl[6], dl[7]);
  } else {
    unsigned dv[8];
#pragma unroll
    for (int k = 0; k < 8; ++k) dv[k] = cvt_pk_bf16(acc[2 * k], acc[2 * k + 1]);
    unsigned short* vp = vb + (size_t)(chunk - 1) * VPLANE + p * 16;
    *(uint4*)(vp + 0) = make_uint4(dv[0], dv[1], dv[2], dv[3]);
    *(uint4*)(vp + 8) = make_uint4(dv[4], dv[5], dv[6], dv[7]);
  }
}

// K2 (R15): BOTH attention passes in ONE 4096-block dispatch.
// mode = bid>>11 (0: row pass -> wo, 1: col pass -> ho). 2048%8==0 so mode-1's
// XCD swizzle behavior is identical to the old standalone dispatch; mode-0
// blocks drain while mode-1 blocks launch -> the inter-attn launch boundary
// and mode-0 tail overlap away (R14 accounting: ~150us of the 476 total was
// dispatch gaps+tails across 6 launches).
// Body = R14: vz XOR-swizzle (bank conflicts 7.34M->1.05M measured), 2-half
// vz (33KB LDS), v prefetch, cvt_pk, Zp partial sums.
__global__ __launch_bounds__(256) void attn_kernel(
    const unsigned short* __restrict__ qh, const unsigned short* __restrict__ ql,
    const unsigned short* __restrict__ kh, const unsigned short* __restrict__ kl,
    const unsigned short* __restrict__ vb,
    _Float16* __restrict__ wo, _Float16* __restrict__ ho) {
  const int bid = blockIdx.x;            // 0..4095
  const int mode = bid >> 11;            // 0: row pass, 1: col pass
  const int inner = bid & 2047;
  const int s = mode ? (((inner & 7) << 8) | (inner >> 3)) : inner;
  _Float16* o = mode ? ho : wo;
  const int t = threadIdx.x; // 0..255
  const int b = s >> 8;
  const int r = s & 255;     // h (row mode) or w (col mode)
  const int w = t >> 6;      // wave 0..3
  const int l = t & 63;      // lane
  const int g = l >> 5;      // lane half
  const int ln = l & 31;

  __shared__ short qs_h[256 * 8], qs_l[256 * 8]; // Q split bf16 [row][8]
  __shared__ short ks_h[256 * 8], ks_l[256 * 8]; // K split bf16
  __shared__ short vz[8192];                     // V*(1/Z) bf16 HALF-tile (16KB)
  __shared__ float Zl[256];                      // 1/Z

  float* Zp = (float*)vz; // Phase-B scratch: [8][256] partials (8 KB of 16 KB)

  size_t qkb, qk_stride;       // short-element offsets into qh/ql/kh/kl
  size_t v_pix_base, v_pix_stride; // PIXEL index into v planes
  if (mode == 0) {
    qkb    = (size_t)s * (Ln * Cq);  qk_stride = Cq;
    v_pix_base = (size_t)s * Ln;     v_pix_stride = 1;
  } else {
    qkb    = ((size_t)b * HWn + r) * Cq;  qk_stride = (size_t)Ln * Cq;
    v_pix_base = (size_t)b * HWn + r;     v_pix_stride = Ln;
  }

  // ---- Phase C address algebra (hoisted; only rnd varies per round) ----
  const int rem_i = t >> 4;          // 0..15
  const int c4 = (t & 15) << 2;      // 0..60
  const int a_ = rem_i >> 3, g2 = (rem_i >> 2) & 1, t0 = rem_i & 3;
  const int e_ = 4 * a_ + t0;
  const int mt_ = c4 >> 5;
  const int lane_s0 = 32 * g2 + (c4 & 31);
  // swizzled write base (bytes), rnd=0,u=0; key = logical bits[9:7]
  const unsigned key_w = (unsigned)((g2 << 2) | ((t & 7) >> 1));
  const unsigned wbase = ((unsigned)(((mt_ * 64 + lane_s0) * 8 + e_) * 2)) ^ (key_w << 4);
  char* vzb = (char*)vz;
  const unsigned short* vp0 = vb + (size_t)(c4 >> 4) * VPLANE +
                              (v_pix_base + (size_t)rem_i * v_pix_stride) * 16 +
                              (c4 & 15);
  const size_t step = (size_t)256 * v_pix_stride; // shorts per round
  // swizzled read lane slot (key_r = (l>>3)&7)
  const int lsw = l ^ ((l >> 3) & 7);

  // ---- Phase A: stage pre-split Q,K rows + prefetch v rounds 0-7 ----
  {
    const size_t off = qkb + (size_t)t * qk_stride;
    *(bf16x8*)&qs_h[t * 8] = *(const bf16x8*)(qh + off);
    *(bf16x8*)&qs_l[t * 8] = *(const bf16x8*)(ql + off);
    *(bf16x8*)&ks_h[t * 8] = *(const bf16x8*)(kh + off);
    *(bf16x8*)&ks_l[t * 8] = *(const bf16x8*)(kl + off);
  }
  u16x4 raw_pre[8]; // 16 VGPRs, live across Phase B
#pragma unroll
  for (int rnd = 0; rnd < 8; ++rnd)
    raw_pre[rnd] = *(const u16x4*)(vp0 + rnd * step);
  __syncthreads();

  // ---- Phase B (sweep 1): St[j][i] tiles; per-(w,g) Z partials ----
  {
    const short* kb = g ? ks_l : ks_h;
    const int wg = (w << 1) | g; // 0..7
    bf16x8 afk0 = *(const bf16x8*)&kb[(ln + 32 * (2 * w + 0)) * 8];
    bf16x8 afk1 = *(const bf16x8*)&kb[(ln + 32 * (2 * w + 1)) * 8];
#pragma unroll 1
    for (int it = 0; it < 8; ++it) {
      int i = ln + 32 * it;
      bf16x8 bh = *(const bf16x8*)&qs_h[i * 8];
      bf16x8 bl = *(const bf16x8*)&qs_l[i * 8];
      float z0 = 0.f, z1 = 0.f, z2 = 0.f, z3 = 0.f; // break the add chain
      {
        f32x16 c = zero16();
        c = __builtin_amdgcn_mfma_f32_32x32x16_bf16(afk0, bh, c, 0, 0, 0);
        c = __builtin_amdgcn_mfma_f32_32x32x16_bf16(afk0, bl, c, 0, 0, 0);
#pragma unroll
        for (int rr = 0; rr < 16; ++rr) {
          float e = fast_exp2(c[rr]);
          if ((rr & 3) == 0) z0 += e; else if ((rr & 3) == 1) z1 += e;
          else if ((rr & 3) == 2) z2 += e; else z3 += e;
        }
      }
      {
        f32x16 c = zero16();
        c = __builtin_amdgcn_mfma_f32_32x32x16_bf16(afk1, bh, c, 0, 0, 0);
        c = __builtin_amdgcn_mfma_f32_32x32x16_bf16(afk1, bl, c, 0, 0, 0);
#pragma unroll
        for (int rr = 0; rr < 16; ++rr) {
          float e = fast_exp2(c[rr]);
          if ((rr & 3) == 0) z0 += e; else if ((rr & 3) == 1) z1 += e;
          else if ((rr & 3) == 2) z2 += e; else z3 += e;
        }
      }
      Zp[(wg << 8) + i] = (z0 + z1) + (z2 + z3);
    }
  }
  __syncthreads();
  {
    float z = 0.f;
#pragma unroll
    for (int k = 0; k < 8; ++k) z += Zp[(k << 8) + t];
    Zl[t] = 1.0f / z;
  }
  __syncthreads(); // Zl visible AND Zp reads done before vz overwrite

  // ---- Phase C1: scale v rounds 0-7 into vz (swizzled); prefetch 8-15 ----
#pragma unroll
  for (int rnd = 0; rnd < 8; ++rnd) {
    float iz = Zl[(rnd << 4) + rem_i];
#pragma unroll
    for (int u = 0; u < 4; ++u) {
      unsigned dd = cvt_pk_bf16(bf2f(raw_pre[rnd][u]) * iz, 0.f);
      *(short*)(vzb + ((wbase ^ (unsigned)(u << 4)) + rnd * 2048)) = (short)dd;
    }
  }
  u16x4 raw2[8];
#pragma unroll
  for (int rnd = 0; rnd < 8; ++rnd)
    raw2[rnd] = *(const u16x4*)(vp0 + (8 + rnd) * step);
  __syncthreads();

  // ---- Phase D: two PV half-sweeps over the 16KB vz ----
  f32x16 acc00 = zero16(), acc01 = zero16(), acc10 = zero16(), acc11 = zero16();
  bf16x8 bkh[2], bkl[2];
#pragma unroll
  for (int nt2 = 0; nt2 < 2; ++nt2) {
    int j = ln + 32 * (2 * w + nt2);
    bkh[nt2] = *(const bf16x8*)&ks_h[j * 8];
    bkl[nt2] = *(const bf16x8*)&ks_l[j * 8];
  }
  const short* qb = g ? qs_l : qs_h;

#pragma unroll
  for (int half = 0; half < 2; ++half) {
#pragma unroll 1
    for (int it = half * 4; it < half * 4 + 4; ++it) {
      int i = ln + 32 * it;
      bf16x8 aQ = *(const bf16x8*)&qb[i * 8];
      bf16x8 pf[2][2]; // [nt2][s2]
#pragma unroll
      for (int nt2 = 0; nt2 < 2; ++nt2) {
        f32x16 c = zero16();
        c = __builtin_amdgcn_mfma_f32_32x32x16_bf16(aQ, bkh[nt2], c, 0, 0, 0);
        c = __builtin_amdgcn_mfma_f32_32x32x16_bf16(aQ, bkl[nt2], c, 0, 0, 0);
        union { unsigned u[4]; bf16x8 v; } cv0, cv1;
#pragma unroll
        for (int k = 0; k < 4; ++k)
          cv0.u[k] = cvt_pk_bf16(fast_exp2(c[2 * k]), fast_exp2(c[2 * k + 1]));
#pragma unroll
        for (int k = 0; k < 4; ++k)
          cv1.u[k] = cvt_pk_bf16(fast_exp2(c[8 + 2 * k]), fast_exp2(c[8 + 2 * k + 1]));
        pf[nt2][0] = cv0.v;
        pf[nt2][1] = cv1.v;
      }
#pragma unroll
      for (int s2 = 0; s2 < 2; ++s2) {
#pragma unroll
        for (int mt = 0; mt < 2; ++mt) {
          bf16x8 vf = *(const bf16x8*)&vz[((((it & 3) * 2 + s2) * 2 + mt) * 64 + lsw) * 8];
          if (mt == 0) {
            acc00 = __builtin_amdgcn_mfma_f32_32x32x16_bf16(vf, pf[0][s2], acc00, 0, 0, 0);
            acc10 = __builtin_amdgcn_mfma_f32_32x32x16_bf16(vf, pf[1][s2], acc10, 0, 0, 0);
          } else {
            acc01 = __builtin_amdgcn_mfma_f32_32x32x16_bf16(vf, pf[0][s2], acc01, 0, 0, 0);
            acc11 = __builtin_amdgcn_mfma_f32_32x32x16_bf16(vf, pf[1][s2], acc11, 0, 0, 0);
          }
        }
      }
    }
    if (half == 0) {
      // refill vz with rounds 8-15 (raw2 already in flight)
      __syncthreads(); // D-half-1 reads done
#pragma unroll
      for (int rnd = 0; rnd < 8; ++rnd) {
        float iz = Zl[((rnd + 8) << 4) + rem_i];
#pragma unroll
        for (int u = 0; u < 4; ++u) {
          unsigned dd = cvt_pk_bf16(bf2f(raw2[rnd][u]) * iz, 0.f);
          *(short*)(vzb + ((wbase ^ (unsigned)(u << 4)) + rnd * 2048)) = (short)dd;
        }
      }
      __syncthreads(); // vz half-2 ready
    }
  }

  // ---- Phase E: store C-layout accs as fp16 ----
  // row c = (reg&3) + 8*(reg>>2) + 4*g + 32*mt ; col j = ln + 32*(2w+nt2)
#pragma unroll
  for (int nt2 = 0; nt2 < 2; ++nt2) {
    int j = ln + 32 * (2 * w + nt2);
#pragma unroll
    for (int mt = 0; mt < 2; ++mt) {
      const f32x16& A = (nt2 == 0) ? (mt == 0 ? acc00 : acc01)
                                   : (mt == 0 ? acc10 : acc11);
#pragma unroll
      for (int reg = 0; reg < 16; ++reg) {
        int c = (reg & 3) + 8 * (reg >> 2) + 4 * g + 32 * mt;
        if (mode == 0) {
          o[((size_t)b * 64 + c) * HWn + (size_t)r * 256 + j] = (_Float16)A[reg];
        } else {
          o[((size_t)s * 64 + c) * 256 + j] = (_Float16)A[reg];
        }
      }
    }
  }
}

// K3: out = gamma*(w_out + h_out^T) + x, fp16 intermediates.
// h-tile = 64 so each 64KB-strided ho row-read is a full 128B line (64 halves).
// LDS [256][66] halves: read addr bank = (t + rr/2)%32 -> 2-way (free).
__global__ __launch_bounds__(256) void merge_kernel(
    const _Float16* __restrict__ wo, const _Float16* __restrict__ ho,
    const float* __restrict__ x, const float* __restrict__ gamma,
    float* __restrict__ out) {
  const int h0 = blockIdx.x * 64;
  const int c = blockIdx.y;
  const int b = blockIdx.z;
  const int t = threadIdx.x;
  __shared__ _Float16 lds[256 * 66]; // [w][hh] padded (33.8 KB)

  const float g = gamma[0];

  // load ho[b][w=0..255][c][h0..h0+63]: 8 lanes cover one w-row (128B line)
#pragma unroll
  for (int it = 0; it < 8; ++it) {
    int e = it * 256 + t;       // 0..2047
    int w = e >> 3, q8 = (e & 7) << 3; // 8 halves (16B) per lane
    uint4 f = *(const uint4*)&ho[(((size_t)b * 256 + w) * 64 + c) * 256 + h0 + q8];
    unsigned* dst = (unsigned*)&lds[w * 66 + q8];
    dst[0] = f.x; dst[1] = f.y; dst[2] = f.z; dst[3] = f.w;
  }
  __syncthreads();

#pragma unroll 4
  for (int rr = 0; rr < 64; ++rr) {
    size_t idx = (((size_t)b * 64 + c) * 256 + h0 + rr) * 256 + t;
    out[idx] = g * ((float)wo[idx] + (float)lds[t * 66 + rr]) + x[idx];
  }
}

extern "C" void kernel_launch(void* const* d_in, const int* in_sizes, int n_in,
                              void* d_out, int out_size, void* d_ws, size_t ws_size,
                              hipStream_t stream) {
  const float* x     = (const float*)d_in[0];
  const float* Wq    = (const float*)d_in[1];
  const float* bq    = (const float*)d_in[2];
  const float* Wk    = (const float*)d_in[3];
  const float* bk    = (const float*)d_in[4];
  const float* Wv    = (const float*)d_in[5];
  const float* bv    = (const float*)d_in[6];
  const float* gamma = (const float*)d_in[7];
  float* out = (float*)d_out;
  char*  ws  = (char*)d_ws;

  float*          wt = (float*)(ws + WT_B);
  unsigned short* qh = (unsigned short*)(ws + QH_B);
  unsigned short* ql = (unsigned short*)(ws + QL_B);
  unsigned short* kh = (unsigned short*)(ws + KH_B);
  unsigned short* kl = (unsigned short*)(ws + KL_B);
  unsigned short* vb = (unsigned short*)(ws + VB_B);
  _Float16*       ho = (_Float16*)(ws + HO_B);
  _Float16*       wo = (_Float16*)(ws + WO_B);

  hipLaunchKernelGGL(pack_weights, dim3(20), dim3(256), 0, stream, Wq, Wk, Wv, wt);
  hipLaunchKernelGGL(qkv_kernel, dim3(10240), dim3(256), 0, stream,
                     x, wt, bq, bk, bv, qh, ql, kh, kl, vb);
  hipLaunchKernelGGL(attn_kernel, dim3(4096), dim3(256), 0, stream,
                     qh, ql, kh, kl, vb, wo, ho); // both passes, one dispatch
  hipLaunchKernelGGL(merge_kernel, dim3(4, 64, 8), dim3(256), 0, stream,
                     wo, ho, x, gamma, out);
}